// Round 15
// baseline (357.115 us; speedup 1.0000x reference)
//
#include <hip/hip_runtime.h>

// B=2, S=2048, E=1024, H=16, DH=64, FF=4096.  All dims hardcoded.
// R23 = R20 verbatim (best measured: 350.1 us). Config-space sampling
//      (R21/R22 XA + split-K recombinations) landed 355-358 — within or
//      behind R20. Locking the best-measured configuration:
//      GEMM1 XA=4 (2D XCD map, 5 MB/XCD near-L2), GEMM3 XA=4,
//      GEMM2/GEMM4 split-K=2 fp32 + fused reduce(+LN), flash attn with
//      XCD-colocated mapping + prefetch-across-barrier + setprio.

typedef __attribute__((ext_vector_type(8))) short short8;
typedef __attribute__((ext_vector_type(4))) float floatx4;

__device__ inline unsigned short f32_to_bf16(float f) {
  unsigned u = __float_as_uint(f);
  unsigned rb = (u >> 16) & 1u;  // round-to-nearest-even
  u += 0x7fffu + rb;
  return (unsigned short)(u >> 16);
}
__device__ inline unsigned f32_to_bf16_hi(float f) {  // round-half-up, cheap
  return (__float_as_uint(f) + 0x8000u) >> 16;
}
__device__ inline float bf16_to_f32(unsigned short u) {
  return __uint_as_float(((unsigned)u) << 16);
}

// async global -> LDS, 16 bytes per lane. LDS dest = wave-uniform base + lane*16.
__device__ inline void gload16(const void* g, void* l) {
  __builtin_amdgcn_global_load_lds(
      (const __attribute__((address_space(1))) void*)g,
      (__attribute__((address_space(3))) void*)l, 16, 0, 0);
}

// ---------------- transpose fp32 [R][C] -> bf16 out[c][r], row stride ldo ---
__global__ __launch_bounds__(256) void transpose_to_bf16(
    const float* __restrict__ in, unsigned short* __restrict__ out,
    int R, int C, int ldo, long in_bs, long out_bs) {
  __shared__ float tile[32][33];
  in  += (size_t)blockIdx.z * in_bs;
  out += (size_t)blockIdx.z * out_bs;
  const int c0 = blockIdx.x * 32, r0 = blockIdx.y * 32;
  const int tx = threadIdx.x & 31, ty = threadIdx.x >> 5;
#pragma unroll
  for (int i = 0; i < 32; i += 8)
    tile[ty + i][tx] = in[(size_t)(r0 + ty + i) * C + c0 + tx];
  __syncthreads();
#pragma unroll
  for (int i = 0; i < 32; i += 8)
    out[(size_t)(c0 + ty + i) * ldo + r0 + tx] = f32_to_bf16(tile[tx][ty + i]);
}

// ---------------- fused Wq/Wk/Wv transpose: z in [0,48) = mat*16 + head -----
__global__ __launch_bounds__(256) void transpose_qkv_to_bf16(
    const float* __restrict__ Wq, const float* __restrict__ Wk,
    const float* __restrict__ Wv, unsigned short* __restrict__ out) {
  __shared__ float tile[32][33];
  const int z = blockIdx.z, m = z >> 4;
  const float* in = (m == 0 ? Wq : (m == 1 ? Wk : Wv)) + (size_t)(z & 15) * 65536;
  unsigned short* o = out + (size_t)z * 65536;  // (m*16+h)*1024*64
  const int c0 = blockIdx.x * 32, r0 = blockIdx.y * 32;  // C=64, R=1024
  const int tx = threadIdx.x & 31, ty = threadIdx.x >> 5;
#pragma unroll
  for (int i = 0; i < 32; i += 8)
    tile[ty + i][tx] = in[(size_t)(r0 + ty + i) * 64 + c0 + tx];
  __syncthreads();
#pragma unroll
  for (int i = 0; i < 32; i += 8)
    o[(size_t)(c0 + ty + i) * 1024 + r0 + tx] = f32_to_bf16(tile[tx][ty + i]);
}

// ---------------- transpose V section of qkv (bf16) -> vT[bh*64+d][2048] ----
__global__ __launch_bounds__(256) void transpose_v(
    const unsigned short* __restrict__ qkv, unsigned short* __restrict__ vT) {
  __shared__ unsigned short tile[32][33];
  const int bh = blockIdx.z, b = bh >> 4, h = bh & 15;
  const int k0 = blockIdx.x * 32, d0 = blockIdx.y * 32;
  const int tx = threadIdx.x & 31, ty = threadIdx.x >> 5;
#pragma unroll
  for (int i = 0; i < 32; i += 8)
    tile[ty + i][tx] = qkv[(size_t)(b * 2048 + k0 + ty + i) * 3072 + 2048 + h * 64 + d0 + tx];
  __syncthreads();
#pragma unroll
  for (int i = 0; i < 32; i += 8)
    vT[((size_t)bh * 64 + d0 + ty + i) * 2048 + k0 + tx] = tile[tx][ty + i];
}

// ---------------- LayerNorm: fp32 [rows][1024] -> bf16, one block per row ---
__global__ __launch_bounds__(256) void layernorm_bf16(
    const float* __restrict__ x, const float* __restrict__ g,
    const float* __restrict__ be, unsigned short* __restrict__ out) {
  const int row = blockIdx.x;
  const int t = threadIdx.x;
  floatx4 v = ((const floatx4*)(x + (size_t)row * 1024))[t];
  float s  = v[0] + v[1] + v[2] + v[3];
  float s2 = v[0]*v[0] + v[1]*v[1] + v[2]*v[2] + v[3]*v[3];
#pragma unroll
  for (int off = 1; off < 64; off <<= 1) {
    s  += __shfl_xor(s, off);
    s2 += __shfl_xor(s2, off);
  }
  __shared__ float red[8];
  const int wave = t >> 6, lane = t & 63;
  if (lane == 0) { red[wave] = s; red[wave + 4] = s2; }
  __syncthreads();
  float ts  = red[0] + red[1] + red[2] + red[3];
  float ts2 = red[4] + red[5] + red[6] + red[7];
  float mu  = ts * (1.f / 1024.f);
  float var = ts2 * (1.f / 1024.f) - mu * mu;
  float rs  = rsqrtf(var + 1e-5f);
  floatx4 gv = ((const floatx4*)g)[t];
  floatx4 bv = ((const floatx4*)be)[t];
  ushort4 ov;
  ov.x = f32_to_bf16((v[0] - mu) * rs * gv[0] + bv[0]);
  ov.y = f32_to_bf16((v[1] - mu) * rs * gv[1] + bv[1]);
  ov.z = f32_to_bf16((v[2] - mu) * rs * gv[2] + bv[2]);
  ov.w = f32_to_bf16((v[3] - mu) * rs * gv[3] + bv[3]);
  ((ushort4*)(out + (size_t)row * 1024))[t] = ov;
}

// ---------------- bf16 MFMA GEMM: C = A[M,Kfull sub Klen] @ Bt^T ------------
// dbuf LDS [2][128][32] linear, global_load_lds width 16, stage-ahead with
// counted vmcnt(4): next tile's 4 DMA loads stay in flight across barrier #1.
// 2D XCD mapping (XA = XCDs along m): per-XCD sub-rectangle of
// (Mpanels/XA) x (NB*XA/8) panels. XA=8 reproduces the legacy strip exactly.
// blockIdx.z = split-K slice (offset z*Klen into K).
// mode 0: bf16 store; 1: fp32 +bias+resid; 2: bf16 relu(+bias); 3: fp32 partial
// bf16 modes (0/2) stage the C tile through LDS, coalesced uint4 stores.
__global__ __launch_bounds__(256, 4) void gemm_bf16(
    const unsigned short* __restrict__ A, const unsigned short* __restrict__ Bt,
    const float* __restrict__ bias, const float* __restrict__ resid,
    void* __restrict__ Cout, int M, int N, int Kfull, int Klen, int mode,
    int XA) {
  __shared__ unsigned short As[2][128 * 32];
  __shared__ unsigned short Bs[2][128 * 32];
  const int t = threadIdx.x;
  const int NB = gridDim.x;  // n-panels; gridDim.y * 128 == M
  const int bid = blockIdx.y * NB + blockIdx.x;
  const int xcd = bid & 7, s = bid >> 3;
  const int mx = (M >> 7) / XA;          // m-panels per XCD
  const int nxp = (NB * XA) >> 3;        // n-panels per XCD
  const int xcd_m = xcd % XA, xcd_n = xcd / XA;
  const int m0 = (xcd_m * mx + s / nxp) * 128;
  const int n0 = (xcd_n * nxp + s % nxp) * 128;
  const int koff = blockIdx.z * Klen;
  const int lane = t & 63, wave = t >> 6;
  const int wm = (wave >> 1) * 64, wn = (wave & 1) * 64;
  const int l15 = lane & 15, quad = lane >> 4;

  floatx4 acc[4][4];
#pragma unroll
  for (int i = 0; i < 4; ++i)
#pragma unroll
    for (int j = 0; j < 4; ++j) acc[i][j] = floatx4{0.f, 0.f, 0.f, 0.f};

  const int srow = wave * 32 + (lane >> 2);
  const int scol = (lane & 3) * 8;
  const unsigned short* Ag0 = A + (size_t)(m0 + srow) * Kfull + koff + scol;
  const unsigned short* Ag1 = Ag0 + (size_t)16 * Kfull;
  const unsigned short* Bg0 = Bt + (size_t)(n0 + srow) * Kfull + koff + scol;
  const unsigned short* Bg1 = Bg0 + (size_t)16 * Kfull;
  const int sbase0 = (wave * 2 + 0) * 512;
  const int sbase1 = (wave * 2 + 1) * 512;

  const int KT = Klen >> 5;
  gload16(Ag0, &As[0][sbase0]);
  gload16(Ag1, &As[0][sbase1]);
  gload16(Bg0, &Bs[0][sbase0]);
  gload16(Bg1, &Bs[0][sbase1]);

  int buf = 0;
  for (int kt = 0; kt < KT; ++kt) {
    if (kt + 1 < KT) {
      const int ko = (kt + 1) * 32;
      gload16(Ag0 + ko, &As[buf ^ 1][sbase0]);
      gload16(Ag1 + ko, &As[buf ^ 1][sbase1]);
      gload16(Bg0 + ko, &Bs[buf ^ 1][sbase0]);
      gload16(Bg1 + ko, &Bs[buf ^ 1][sbase1]);
      asm volatile("s_waitcnt vmcnt(4)" ::: "memory");
    } else {
      asm volatile("s_waitcnt vmcnt(0)" ::: "memory");
    }
    __builtin_amdgcn_s_barrier();
    short8 a[4], b[4];
#pragma unroll
    for (int i = 0; i < 4; ++i)
      a[i] = *(const short8*)&As[buf][(wm + i * 16 + l15) * 32 + quad * 8];
#pragma unroll
    for (int i = 0; i < 4; ++i)
      b[i] = *(const short8*)&Bs[buf][(wn + i * 16 + l15) * 32 + quad * 8];
#pragma unroll
    for (int i = 0; i < 4; ++i)
#pragma unroll
      for (int j = 0; j < 4; ++j)
        acc[i][j] = __builtin_amdgcn_mfma_f32_16x16x32_bf16(a[i], b[j], acc[i][j], 0, 0, 0);
    __builtin_amdgcn_s_barrier();
    buf ^= 1;
  }
  __builtin_amdgcn_sched_barrier(0);

  if (mode == 0 || mode == 2) {
    // ---- coalesced bf16 epilogue: stage C half-tiles (64x128, 16 KB) in As.
    unsigned short* Cs = &As[0][0];  // 8192 halfs
#pragma unroll
    for (int p = 0; p < 2; ++p) {
      if ((wm >> 6) == p) {  // waves owning rows [p*64, p*64+64)
#pragma unroll
        for (int i = 0; i < 4; ++i)
#pragma unroll
          for (int j = 0; j < 4; ++j)
#pragma unroll
            for (int r = 0; r < 4; ++r) {
              const int rl = i * 16 + quad * 4 + r;       // 0..63 within half
              float v = acc[i][j][r];
              if (mode == 2) {
                v += bias[n0 + wn + j * 16 + l15];
                v = fmaxf(v, 0.f);
              }
              Cs[rl * 128 + wn + j * 16 + l15] = f32_to_bf16(v);
            }
      }
      __syncthreads();
      // store 16 KB as 1024 uint4 chunks: full 64B lines, coalesced
#pragma unroll
      for (int c = 0; c < 4; ++c) {
        const int idx = c * 256 + t;          // 0..1023
        const int row = idx >> 4, chunk = idx & 15;
        *(uint4*)&((unsigned short*)Cout)[(size_t)(m0 + p * 64 + row) * N + n0 + chunk * 8] =
            *(const uint4*)&Cs[row * 128 + chunk * 8];
      }
      __syncthreads();
    }
  } else {
    const size_t poff = (size_t)blockIdx.z * 4096 * 1024;  // partial slab
#pragma unroll
    for (int i = 0; i < 4; ++i)
#pragma unroll
      for (int j = 0; j < 4; ++j) {
        const int col = n0 + wn + j * 16 + l15;
        const int rb = m0 + wm + i * 16 + quad * 4;
#pragma unroll
        for (int r = 0; r < 4; ++r) {
          const int row = rb + r;
          float v = acc[i][j][r];
          if (mode == 1) {
            v += bias[col] + resid[(size_t)row * N + col];
            ((float*)Cout)[(size_t)row * N + col] = v;
          } else {
            ((float*)Cout)[poff + (size_t)row * N + col] = v;
          }
        }
      }
  }
}

// ---------------- split-K reduce: out = p0 + p1 + bias + resid  (N=1024) ----
__global__ __launch_bounds__(256) void splitk_reduce(
    const float* __restrict__ p, const float* __restrict__ bias,
    const float* __restrict__ resid, float* __restrict__ out) {
  const int t = threadIdx.x;                  // 256 float4 per row
  const size_t base = (size_t)blockIdx.x * 256 + t;
  floatx4 a = ((const floatx4*)p)[base];
  floatx4 b = ((const floatx4*)p)[1048576 + base];  // + M*N/4
  floatx4 rv = ((const floatx4*)resid)[base];
  floatx4 bv = ((const floatx4*)bias)[t];
  ((floatx4*)out)[base] = a + b + rv + bv;
}

// ---------------- fused split-K=2 reduce + LayerNorm (GEMM2 -> x1 -> nx2) ---
__global__ __launch_bounds__(256) void splitk_reduce_ln(
    const float* __restrict__ p, const float* __restrict__ bias,
    const float* __restrict__ resid, const float* __restrict__ g,
    const float* __restrict__ be, float* __restrict__ xout,
    unsigned short* __restrict__ nxout) {
  const int row = blockIdx.x, t = threadIdx.x;
  const size_t base = (size_t)row * 256 + t;
  floatx4 a = ((const floatx4*)p)[base];
  floatx4 b = ((const floatx4*)p)[1048576 + base];  // + M*N/4
  floatx4 rv = ((const floatx4*)resid)[base];
  floatx4 bv = ((const floatx4*)bias)[t];
  floatx4 v = a + b + rv + bv;
  ((floatx4*)xout)[base] = v;
  float s  = v[0] + v[1] + v[2] + v[3];
  float s2 = v[0]*v[0] + v[1]*v[1] + v[2]*v[2] + v[3]*v[3];
#pragma unroll
  for (int off = 1; off < 64; off <<= 1) {
    s  += __shfl_xor(s, off);
    s2 += __shfl_xor(s2, off);
  }
  __shared__ float red[8];
  const int wave = t >> 6, lane = t & 63;
  if (lane == 0) { red[wave] = s; red[wave + 4] = s2; }
  __syncthreads();
  float ts  = red[0] + red[1] + red[2] + red[3];
  float ts2 = red[4] + red[5] + red[6] + red[7];
  float mu  = ts * (1.f / 1024.f);
  float var = ts2 * (1.f / 1024.f) - mu * mu;
  float rs  = rsqrtf(var + 1e-5f);
  floatx4 gv = ((const floatx4*)g)[t];
  floatx4 bev = ((const floatx4*)be)[t];
  ushort4 ov;
  ov.x = f32_to_bf16((v[0] - mu) * rs * gv[0] + bev[0]);
  ov.y = f32_to_bf16((v[1] - mu) * rs * gv[1] + bev[1]);
  ov.z = f32_to_bf16((v[2] - mu) * rs * gv[2] + bev[2]);
  ov.w = f32_to_bf16((v[3] - mu) * rs * gv[3] + bev[3]);
  ((ushort4*)(nxout + (size_t)row * 1024))[t] = ov;
}

// ---------------- MFMA flash attention, causal ------------------------------
// 128 q-rows/block, 4 waves x 32 rows. Fixed-base softmax (p=exp(S)). LDS
// stride 68 halfs: 52.2 KB -> 3 blocks/CU. XCD-colocated block mapping;
// raw s_barrier with lgkmcnt(0) only (prefetch spans barrier); setprio.
__global__ __launch_bounds__(256, 3) void flash_attn_mfma(
    const unsigned short* __restrict__ qkv,
    const unsigned short* __restrict__ vT,
    unsigned short* __restrict__ attn) {
  const int id = blockIdx.x;
  const int xcd = id & 7, slot = id >> 3;      // 64 slots per XCD class
  const int bh = xcd * 4 + (slot & 3);         // 4 (b,h) pairs per XCD
  const int qt = 15 - (slot >> 2);             // biggest first
  const int b = bh >> 4, h = bh & 15;
  const int q0 = qt * 128;
  const int t = threadIdx.x;
  const int wave = t >> 6, lane = t & 63;
  const int l15 = lane & 15, quad = lane >> 4;

  __shared__ unsigned short Ks[2][64][68];   // [buf][key][d]
  __shared__ unsigned short Vs[2][64][68];   // [buf][d][key]
  __shared__ unsigned short Ps[4][32][68];   // per-wave P [q][key]

  const size_t qbase = (size_t)b * 2048 * 3072;
  const int qrow_w = q0 + wave * 32;
  const unsigned short* Kbase = qkv + qbase + 1024 + h * 64;  // stride 3072
  const unsigned short* Vbase = vT + (size_t)bh * 64 * 2048;  // stride 2048

  // Q frags (rows mf*16+l15, scaled by 1/8 exactly)
  short8 qf[2][2];
#pragma unroll
  for (int mf = 0; mf < 2; ++mf)
#pragma unroll
    for (int kc = 0; kc < 2; ++kc) {
      short8 raw = *(const short8*)(qkv + qbase +
          (size_t)(qrow_w + mf * 16 + l15) * 3072 + h * 64 + kc * 32 + quad * 8);
      short8 sc;
#pragma unroll
      for (int j = 0; j < 8; ++j)
        sc[j] = (short)f32_to_bf16(bf16_to_f32((unsigned short)raw[j]) * 0.125f);
      qf[mf][kc] = sc;
    }

  floatx4 o[2][4];
  float l_s[2] = {0.f, 0.f};  // per-lane partial row-sum for q = mf*16+l15
#pragma unroll
  for (int mf = 0; mf < 2; ++mf)
#pragma unroll
    for (int jd = 0; jd < 4; ++jd) o[mf][jd] = floatx4{0.f, 0.f, 0.f, 0.f};

  const int sr = t >> 3, so = (t & 7) * 8;  // staging rows sr, sr+32

  // prefetch tile 0
  uint4 kr0 = *(const uint4*)(Kbase + (size_t)sr * 3072 + so);
  uint4 kr1 = *(const uint4*)(Kbase + (size_t)(sr + 32) * 3072 + so);
  uint4 vr0 = *(const uint4*)(Vbase + (size_t)sr * 2048 + so);
  uint4 vr1 = *(const uint4*)(Vbase + (size_t)(sr + 32) * 2048 + so);

  const int ntiles = 2 * qt + 2;
  int buf = 0;
  for (int kt = 0; kt < ntiles; ++kt) {
    const int k0 = kt * 64;
    *(uint4*)&Ks[buf][sr][so]      = kr0;
    *(uint4*)&Ks[buf][sr + 32][so] = kr1;
    *(uint4*)&Vs[buf][sr][so]      = vr0;
    *(uint4*)&Vs[buf][sr + 32][so] = vr1;
    if (kt + 1 < ntiles) {
      const int k1 = k0 + 64;
      kr0 = *(const uint4*)(Kbase + (size_t)(k1 + sr) * 3072 + so);
      kr1 = *(const uint4*)(Kbase + (size_t)(k1 + sr + 32) * 3072 + so);
      vr0 = *(const uint4*)(Vbase + (size_t)sr * 2048 + k1 + so);
      vr1 = *(const uint4*)(Vbase + (size_t)(sr + 32) * 2048 + k1 + so);
    }
    asm volatile("s_waitcnt lgkmcnt(0)" ::: "memory");  // LDS writes visible
    __builtin_amdgcn_s_barrier();

    if (k0 <= qrow_w + 31) {  // wave-uniform skip of all-masked tiles
      short8 kf[2][4];
#pragma unroll
      for (int kc = 0; kc < 2; ++kc)
#pragma unroll
        for (int jb = 0; jb < 4; ++jb)
          kf[kc][jb] = *(const short8*)&Ks[buf][jb * 16 + l15][kc * 32 + quad * 8];

      // S^T: st[mf][jb] : D[row=key=jb*16+quad*4+r][col=q=mf*16+l15]
      floatx4 st[2][4];
#pragma unroll
      for (int mf = 0; mf < 2; ++mf)
#pragma unroll
        for (int jb = 0; jb < 4; ++jb) st[mf][jb] = floatx4{0.f, 0.f, 0.f, 0.f};
      __builtin_amdgcn_s_setprio(1);
#pragma unroll
      for (int kc = 0; kc < 2; ++kc)
#pragma unroll
        for (int jb = 0; jb < 4; ++jb) {
#pragma unroll
          for (int mf = 0; mf < 2; ++mf)
            st[mf][jb] = __builtin_amdgcn_mfma_f32_16x16x32_bf16(
                kf[kc][jb], qf[mf][kc], st[mf][jb], 0, 0, 0);
        }
      __builtin_amdgcn_s_setprio(0);

      // exp + causal mask + l accumulation + pack to Ps (b64 per (mf,jb))
#pragma unroll
      for (int mf = 0; mf < 2; ++mf) {
        const int qq = qrow_w + mf * 16 + l15;
#pragma unroll
        for (int jb = 0; jb < 4; ++jb) {
          const int keyb = k0 + jb * 16 + quad * 4;
          float p0 = (keyb + 0 > qq) ? 0.f : __expf(st[mf][jb][0]);
          float p1 = (keyb + 1 > qq) ? 0.f : __expf(st[mf][jb][1]);
          float p2 = (keyb + 2 > qq) ? 0.f : __expf(st[mf][jb][2]);
          float p3 = (keyb + 3 > qq) ? 0.f : __expf(st[mf][jb][3]);
          l_s[mf] += (p0 + p1) + (p2 + p3);
          uint2 pk;
          pk.x = (f32_to_bf16_hi(p1) << 16) | f32_to_bf16_hi(p0);
          pk.y = (f32_to_bf16_hi(p3) << 16) | f32_to_bf16_hi(p2);
          *(uint2*)&Ps[wave][mf * 16 + l15][jb * 16 + quad * 4] = pk;
        }
      }

      // O += P V : 16 MFMAs
      __builtin_amdgcn_s_setprio(1);
#pragma unroll
      for (int kc = 0; kc < 2; ++kc) {
        short8 pf0 = *(const short8*)&Ps[wave][l15][kc * 32 + quad * 8];
        short8 pf1 = *(const short8*)&Ps[wave][16 + l15][kc * 32 + quad * 8];
#pragma unroll
        for (int jd = 0; jd < 4; ++jd) {
          short8 vf = *(const short8*)&Vs[buf][jd * 16 + l15][kc * 32 + quad * 8];
          o[0][jd] = __builtin_amdgcn_mfma_f32_16x16x32_bf16(pf0, vf, o[0][jd], 0, 0, 0);
          o[1][jd] = __builtin_amdgcn_mfma_f32_16x16x32_bf16(pf1, vf, o[1][jd], 0, 0, 0);
        }
      }
      __builtin_amdgcn_s_setprio(0);
    }
    buf ^= 1;
  }

  // final l reduce across the 4 quads holding the same l15
#pragma unroll
  for (int mf = 0; mf < 2; ++mf) {
    l_s[mf] += __shfl_xor(l_s[mf], 16);
    l_s[mf] += __shfl_xor(l_s[mf], 32);
  }

  // epilogue: o row q = mf*16 + quad*4 + r; l for that q lives at lane (quad*4+r)
#pragma unroll
  for (int mf = 0; mf < 2; ++mf)
#pragma unroll
    for (int r = 0; r < 4; ++r) {
      const int qloc = quad * 4 + r;
      const float lsum = __shfl(l_s[mf], qloc);
      const float rl = 1.f / lsum;
      const int row = b * 2048 + q0 + wave * 32 + mf * 16 + qloc;
#pragma unroll
      for (int jd = 0; jd < 4; ++jd)
        attn[(size_t)row * 1024 + h * 64 + jd * 16 + l15] =
            f32_to_bf16(o[mf][jd][r] * rl);
    }
}

// ---------------------------------------------------------------------------
extern "C" void kernel_launch(void* const* d_in, const int* in_sizes, int n_in,
                              void* d_out, int out_size, void* d_ws, size_t ws_size,
                              hipStream_t stream) {
  const float* x   = (const float*)d_in[0];
  const float* Wq  = (const float*)d_in[1];
  const float* Wk  = (const float*)d_in[2];
  const float* Wv  = (const float*)d_in[3];
  const float* Wo  = (const float*)d_in[4];
  const float* bo  = (const float*)d_in[5];
  const float* W1  = (const float*)d_in[6];
  const float* b1  = (const float*)d_in[7];
  const float* W2  = (const float*)d_in[8];
  const float* b2  = (const float*)d_in[9];
  const float* g1  = (const float*)d_in[10];
  const float* be1 = (const float*)d_in[11];
  const float* g2  = (const float*)d_in[12];
  const float* be2 = (const float*)d_in[13];
  float* out = (float*)d_out;

  char* ws = (char*)d_ws;
  size_t off = 0;
  auto alloc = [&](size_t bytes) -> void* {
    void* p = ws + off;
    off += (bytes + 255) & ~(size_t)255;
    return p;
  };
  unsigned short* WqkvT = (unsigned short*)alloc(3072ull * 1024 * 2);
  unsigned short* WoT   = (unsigned short*)alloc(1024ull * 1024 * 2);
  unsigned short* W1T   = (unsigned short*)alloc(4096ull * 1024 * 2);
  unsigned short* W2T   = (unsigned short*)alloc(1024ull * 4096 * 2);
  unsigned short* nx    = (unsigned short*)alloc(4096ull * 1024 * 2);   // 8 MB
  unsigned short* qkv   = (unsigned short*)alloc(4096ull * 3072 * 2);   // 24 MB
  unsigned short* attn  = (unsigned short*)alloc(4096ull * 1024 * 2);
  float*          x1    = (float*)alloc(4096ull * 1024 * 4);
  unsigned short* nx2   = (unsigned short*)alloc(4096ull * 1024 * 2);
  unsigned short* hbuf  = (unsigned short*)alloc(4096ull * 4096 * 2);
  // vT (8 MB) aliases hbuf: vT dead before GEMM3 writes hbuf
  unsigned short* vT    = hbuf;
  // split-K fp32 partials (2 x 16 MB) alias nx+qkv (both dead when used:
  // nx dead after GEMM1; qkv dead after flash; region = exactly 32 MB)
  float*          part  = (float*)nx;

  dim3 blk(256);
  transpose_qkv_to_bf16<<<dim3(2, 32, 48), blk, 0, stream>>>(Wq, Wk, Wv, WqkvT);
  transpose_to_bf16<<<dim3(32, 32, 1), blk, 0, stream>>>(Wo, WoT, 1024, 1024, 1024, 0, 0);
  transpose_to_bf16<<<dim3(128, 32, 1), blk, 0, stream>>>(W1, W1T, 1024, 4096, 1024, 0, 0);
  transpose_to_bf16<<<dim3(32, 128, 1), blk, 0, stream>>>(W2, W2T, 4096, 1024, 4096, 0, 0);

  layernorm_bf16<<<4096, blk, 0, stream>>>(x, g1, be1, nx);
  // GEMM1: 4096x3072x1024 -> bf16 qkv  (2D XCD map: 8m x 12n per XCD)
  gemm_bf16<<<dim3(24, 32, 1), blk, 0, stream>>>(nx, WqkvT, nullptr, nullptr, qkv, 4096, 3072, 1024, 1024, 0, 4);
  transpose_v<<<dim3(64, 2, 32), blk, 0, stream>>>(qkv, vT);
  flash_attn_mfma<<<dim3(512, 1, 1), blk, 0, stream>>>(qkv, vT, attn);
  // GEMM2 split-K=2 (fp32 partials) -> fused reduce+LN  (legacy map, L2-fit)
  gemm_bf16<<<dim3(8, 32, 2), blk, 0, stream>>>(attn, WoT, nullptr, nullptr, part, 4096, 1024, 1024, 512, 3, 8);
  splitk_reduce_ln<<<4096, blk, 0, stream>>>(part, bo, x, g2, be2, x1, nx2);
  // GEMM3: 4096x4096x1024 relu+bias -> bf16 hbuf  (2D XCD map: 8m x 16n per XCD)
  gemm_bf16<<<dim3(32, 32, 1), blk, 0, stream>>>(nx2, W1T, b1, nullptr, hbuf, 4096, 4096, 1024, 1024, 2, 4);
  // GEMM4 split-K=2 (fp32 partials) -> reduce  (legacy map, L2-fit)
  gemm_bf16<<<dim3(8, 32, 2), blk, 0, stream>>>(hbuf, W2T, nullptr, nullptr, part, 4096, 1024, 4096, 2048, 3, 8);
  splitk_reduce<<<4096, blk, 0, stream>>>(part, b2, x1, out);
}

// Round 16
// 350.539 us; speedup vs baseline: 1.0188x; 1.0188x over previous
//
#include <hip/hip_runtime.h>

// B=2, S=2048, E=1024, H=16, DH=64, FF=4096.  All dims hardcoded.
// R24 (final): R20/R23 config + all four weight transposes merged into ONE
//      flat-grid launch (12288 blocks) — removes 3 launch/drain boundaries,
//      zero change to any compute kernel. Session conclusion: configs from
//      R12 on all sample ~353±4 us (cross-run dispatch variance ±8 us);
//      the 128^2 2-phase GEMM structure is pinned at MfmaUtil ~23% (m233
//      ceiling); escaping it needs the faithful 8-phase rebuild.

typedef __attribute__((ext_vector_type(8))) short short8;
typedef __attribute__((ext_vector_type(4))) float floatx4;

__device__ inline unsigned short f32_to_bf16(float f) {
  unsigned u = __float_as_uint(f);
  unsigned rb = (u >> 16) & 1u;  // round-to-nearest-even
  u += 0x7fffu + rb;
  return (unsigned short)(u >> 16);
}
__device__ inline unsigned f32_to_bf16_hi(float f) {  // round-half-up, cheap
  return (__float_as_uint(f) + 0x8000u) >> 16;
}
__device__ inline float bf16_to_f32(unsigned short u) {
  return __uint_as_float(((unsigned)u) << 16);
}

// async global -> LDS, 16 bytes per lane. LDS dest = wave-uniform base + lane*16.
__device__ inline void gload16(const void* g, void* l) {
  __builtin_amdgcn_global_load_lds(
      (const __attribute__((address_space(1))) void*)g,
      (__attribute__((address_space(3))) void*)l, 16, 0, 0);
}

// ---------------- ALL weight transposes, one launch: fp32 -> bf16 ----------
// flat grid 12288 blocks of 256:
//   [0,3072):  Wq/Wk/Wv  per z in [0,48): in (z&15)*65536 of mat z>>4,
//              C=64, ldo=1024, 64 blocks/z (2 x 32)
//   [3072,4096): Wo  1024x1024 -> 1024x1024   (32 x 32)
//   [4096,8192): W1  1024x4096 -> 4096x1024   (128 x 32)
//   [8192,12288): W2 4096x1024 -> 1024x4096   (32 x 128)
__global__ __launch_bounds__(256) void transpose_weights_all(
    const float* __restrict__ Wq, const float* __restrict__ Wk,
    const float* __restrict__ Wv, const float* __restrict__ Wo,
    const float* __restrict__ W1, const float* __restrict__ W2,
    unsigned short* __restrict__ WqkvT, unsigned short* __restrict__ WoT,
    unsigned short* __restrict__ W1T, unsigned short* __restrict__ W2T) {
  __shared__ float tile[32][33];
  const int b = blockIdx.x;
  const float* in;
  unsigned short* out;
  int C, ldo, c0, r0;
  if (b < 3072) {
    const int z = b >> 6, rem = b & 63, m = z >> 4;
    in  = (m == 0 ? Wq : (m == 1 ? Wk : Wv)) + (size_t)(z & 15) * 65536;
    out = WqkvT + (size_t)z * 65536;
    C = 64; ldo = 1024;
    c0 = (rem & 1) * 32; r0 = (rem >> 1) * 32;
  } else if (b < 4096) {
    const int idx = b - 3072;
    in = Wo; out = WoT; C = 1024; ldo = 1024;
    c0 = (idx & 31) * 32; r0 = (idx >> 5) * 32;
  } else if (b < 8192) {
    const int idx = b - 4096;
    in = W1; out = W1T; C = 4096; ldo = 1024;
    c0 = (idx & 127) * 32; r0 = (idx >> 7) * 32;
  } else {
    const int idx = b - 8192;
    in = W2; out = W2T; C = 1024; ldo = 4096;
    c0 = (idx & 31) * 32; r0 = (idx >> 5) * 32;
  }
  const int tx = threadIdx.x & 31, ty = threadIdx.x >> 5;
#pragma unroll
  for (int i = 0; i < 32; i += 8)
    tile[ty + i][tx] = in[(size_t)(r0 + ty + i) * C + c0 + tx];
  __syncthreads();
#pragma unroll
  for (int i = 0; i < 32; i += 8)
    out[(size_t)(c0 + ty + i) * ldo + r0 + tx] = f32_to_bf16(tile[tx][ty + i]);
}

// ---------------- transpose V section of qkv (bf16) -> vT[bh*64+d][2048] ----
__global__ __launch_bounds__(256) void transpose_v(
    const unsigned short* __restrict__ qkv, unsigned short* __restrict__ vT) {
  __shared__ unsigned short tile[32][33];
  const int bh = blockIdx.z, b = bh >> 4, h = bh & 15;
  const int k0 = blockIdx.x * 32, d0 = blockIdx.y * 32;
  const int tx = threadIdx.x & 31, ty = threadIdx.x >> 5;
#pragma unroll
  for (int i = 0; i < 32; i += 8)
    tile[ty + i][tx] = qkv[(size_t)(b * 2048 + k0 + ty + i) * 3072 + 2048 + h * 64 + d0 + tx];
  __syncthreads();
#pragma unroll
  for (int i = 0; i < 32; i += 8)
    vT[((size_t)bh * 64 + d0 + ty + i) * 2048 + k0 + tx] = tile[tx][ty + i];
}

// ---------------- LayerNorm: fp32 [rows][1024] -> bf16, one block per row ---
__global__ __launch_bounds__(256) void layernorm_bf16(
    const float* __restrict__ x, const float* __restrict__ g,
    const float* __restrict__ be, unsigned short* __restrict__ out) {
  const int row = blockIdx.x;
  const int t = threadIdx.x;
  floatx4 v = ((const floatx4*)(x + (size_t)row * 1024))[t];
  float s  = v[0] + v[1] + v[2] + v[3];
  float s2 = v[0]*v[0] + v[1]*v[1] + v[2]*v[2] + v[3]*v[3];
#pragma unroll
  for (int off = 1; off < 64; off <<= 1) {
    s  += __shfl_xor(s, off);
    s2 += __shfl_xor(s2, off);
  }
  __shared__ float red[8];
  const int wave = t >> 6, lane = t & 63;
  if (lane == 0) { red[wave] = s; red[wave + 4] = s2; }
  __syncthreads();
  float ts  = red[0] + red[1] + red[2] + red[3];
  float ts2 = red[4] + red[5] + red[6] + red[7];
  float mu  = ts * (1.f / 1024.f);
  float var = ts2 * (1.f / 1024.f) - mu * mu;
  float rs  = rsqrtf(var + 1e-5f);
  floatx4 gv = ((const floatx4*)g)[t];
  floatx4 bv = ((const floatx4*)be)[t];
  ushort4 ov;
  ov.x = f32_to_bf16((v[0] - mu) * rs * gv[0] + bv[0]);
  ov.y = f32_to_bf16((v[1] - mu) * rs * gv[1] + bv[1]);
  ov.z = f32_to_bf16((v[2] - mu) * rs * gv[2] + bv[2]);
  ov.w = f32_to_bf16((v[3] - mu) * rs * gv[3] + bv[3]);
  ((ushort4*)(out + (size_t)row * 1024))[t] = ov;
}

// ---------------- bf16 MFMA GEMM: C = A[M,Kfull sub Klen] @ Bt^T ------------
// dbuf LDS [2][128][32] linear, global_load_lds width 16, stage-ahead with
// counted vmcnt(4): next tile's 4 DMA loads stay in flight across barrier #1.
// 2D XCD mapping (XA = XCDs along m); XA=8 == legacy strip exactly.
// blockIdx.z = split-K slice (offset z*Klen into K).
// mode 0: bf16 store; 1: fp32 +bias+resid; 2: bf16 relu(+bias); 3: fp32 partial
// bf16 modes (0/2) stage the C tile through LDS, coalesced uint4 stores.
__global__ __launch_bounds__(256, 4) void gemm_bf16(
    const unsigned short* __restrict__ A, const unsigned short* __restrict__ Bt,
    const float* __restrict__ bias, const float* __restrict__ resid,
    void* __restrict__ Cout, int M, int N, int Kfull, int Klen, int mode,
    int XA) {
  __shared__ unsigned short As[2][128 * 32];
  __shared__ unsigned short Bs[2][128 * 32];
  const int t = threadIdx.x;
  const int NB = gridDim.x;  // n-panels; gridDim.y * 128 == M
  const int bid = blockIdx.y * NB + blockIdx.x;
  const int xcd = bid & 7, s = bid >> 3;
  const int mx = (M >> 7) / XA;          // m-panels per XCD
  const int nxp = (NB * XA) >> 3;        // n-panels per XCD
  const int xcd_m = xcd % XA, xcd_n = xcd / XA;
  const int m0 = (xcd_m * mx + s / nxp) * 128;
  const int n0 = (xcd_n * nxp + s % nxp) * 128;
  const int koff = blockIdx.z * Klen;
  const int lane = t & 63, wave = t >> 6;
  const int wm = (wave >> 1) * 64, wn = (wave & 1) * 64;
  const int l15 = lane & 15, quad = lane >> 4;

  floatx4 acc[4][4];
#pragma unroll
  for (int i = 0; i < 4; ++i)
#pragma unroll
    for (int j = 0; j < 4; ++j) acc[i][j] = floatx4{0.f, 0.f, 0.f, 0.f};

  const int srow = wave * 32 + (lane >> 2);
  const int scol = (lane & 3) * 8;
  const unsigned short* Ag0 = A + (size_t)(m0 + srow) * Kfull + koff + scol;
  const unsigned short* Ag1 = Ag0 + (size_t)16 * Kfull;
  const unsigned short* Bg0 = Bt + (size_t)(n0 + srow) * Kfull + koff + scol;
  const unsigned short* Bg1 = Bg0 + (size_t)16 * Kfull;
  const int sbase0 = (wave * 2 + 0) * 512;
  const int sbase1 = (wave * 2 + 1) * 512;

  const int KT = Klen >> 5;
  gload16(Ag0, &As[0][sbase0]);
  gload16(Ag1, &As[0][sbase1]);
  gload16(Bg0, &Bs[0][sbase0]);
  gload16(Bg1, &Bs[0][sbase1]);

  int buf = 0;
  for (int kt = 0; kt < KT; ++kt) {
    if (kt + 1 < KT) {
      const int ko = (kt + 1) * 32;
      gload16(Ag0 + ko, &As[buf ^ 1][sbase0]);
      gload16(Ag1 + ko, &As[buf ^ 1][sbase1]);
      gload16(Bg0 + ko, &Bs[buf ^ 1][sbase0]);
      gload16(Bg1 + ko, &Bs[buf ^ 1][sbase1]);
      asm volatile("s_waitcnt vmcnt(4)" ::: "memory");
    } else {
      asm volatile("s_waitcnt vmcnt(0)" ::: "memory");
    }
    __builtin_amdgcn_s_barrier();
    short8 a[4], b[4];
#pragma unroll
    for (int i = 0; i < 4; ++i)
      a[i] = *(const short8*)&As[buf][(wm + i * 16 + l15) * 32 + quad * 8];
#pragma unroll
    for (int i = 0; i < 4; ++i)
      b[i] = *(const short8*)&Bs[buf][(wn + i * 16 + l15) * 32 + quad * 8];
#pragma unroll
    for (int i = 0; i < 4; ++i)
#pragma unroll
      for (int j = 0; j < 4; ++j)
        acc[i][j] = __builtin_amdgcn_mfma_f32_16x16x32_bf16(a[i], b[j], acc[i][j], 0, 0, 0);
    __builtin_amdgcn_s_barrier();
    buf ^= 1;
  }
  __builtin_amdgcn_sched_barrier(0);

  if (mode == 0 || mode == 2) {
    // ---- coalesced bf16 epilogue: stage C half-tiles (64x128, 16 KB) in As.
    unsigned short* Cs = &As[0][0];  // 8192 halfs
#pragma unroll
    for (int p = 0; p < 2; ++p) {
      if ((wm >> 6) == p) {  // waves owning rows [p*64, p*64+64)
#pragma unroll
        for (int i = 0; i < 4; ++i)
#pragma unroll
          for (int j = 0; j < 4; ++j)
#pragma unroll
            for (int r = 0; r < 4; ++r) {
              const int rl = i * 16 + quad * 4 + r;       // 0..63 within half
              float v = acc[i][j][r];
              if (mode == 2) {
                v += bias[n0 + wn + j * 16 + l15];
                v = fmaxf(v, 0.f);
              }
              Cs[rl * 128 + wn + j * 16 + l15] = f32_to_bf16(v);
            }
      }
      __syncthreads();
      // store 16 KB as 1024 uint4 chunks: full 64B lines, coalesced
#pragma unroll
      for (int c = 0; c < 4; ++c) {
        const int idx = c * 256 + t;          // 0..1023
        const int row = idx >> 4, chunk = idx & 15;
        *(uint4*)&((unsigned short*)Cout)[(size_t)(m0 + p * 64 + row) * N + n0 + chunk * 8] =
            *(const uint4*)&Cs[row * 128 + chunk * 8];
      }
      __syncthreads();
    }
  } else {
    const size_t poff = (size_t)blockIdx.z * 4096 * 1024;  // partial slab
#pragma unroll
    for (int i = 0; i < 4; ++i)
#pragma unroll
      for (int j = 0; j < 4; ++j) {
        const int col = n0 + wn + j * 16 + l15;
        const int rb = m0 + wm + i * 16 + quad * 4;
#pragma unroll
        for (int r = 0; r < 4; ++r) {
          const int row = rb + r;
          float v = acc[i][j][r];
          if (mode == 1) {
            v += bias[col] + resid[(size_t)row * N + col];
            ((float*)Cout)[(size_t)row * N + col] = v;
          } else {
            ((float*)Cout)[poff + (size_t)row * N + col] = v;
          }
        }
      }
  }
}

// ---------------- split-K reduce: out = p0 + p1 + bias + resid  (N=1024) ----
__global__ __launch_bounds__(256) void splitk_reduce(
    const float* __restrict__ p, const float* __restrict__ bias,
    const float* __restrict__ resid, float* __restrict__ out) {
  const int t = threadIdx.x;                  // 256 float4 per row
  const size_t base = (size_t)blockIdx.x * 256 + t;
  floatx4 a = ((const floatx4*)p)[base];
  floatx4 b = ((const floatx4*)p)[1048576 + base];  // + M*N/4
  floatx4 rv = ((const floatx4*)resid)[base];
  floatx4 bv = ((const floatx4*)bias)[t];
  ((floatx4*)out)[base] = a + b + rv + bv;
}

// ---------------- fused split-K=2 reduce + LayerNorm (GEMM2 -> x1 -> nx2) ---
__global__ __launch_bounds__(256) void splitk_reduce_ln(
    const float* __restrict__ p, const float* __restrict__ bias,
    const float* __restrict__ resid, const float* __restrict__ g,
    const float* __restrict__ be, float* __restrict__ xout,
    unsigned short* __restrict__ nxout) {
  const int row = blockIdx.x, t = threadIdx.x;
  const size_t base = (size_t)row * 256 + t;
  floatx4 a = ((const floatx4*)p)[base];
  floatx4 b = ((const floatx4*)p)[1048576 + base];  // + M*N/4
  floatx4 rv = ((const floatx4*)resid)[base];
  floatx4 bv = ((const floatx4*)bias)[t];
  floatx4 v = a + b + rv + bv;
  ((floatx4*)xout)[base] = v;
  float s  = v[0] + v[1] + v[2] + v[3];
  float s2 = v[0]*v[0] + v[1]*v[1] + v[2]*v[2] + v[3]*v[3];
#pragma unroll
  for (int off = 1; off < 64; off <<= 1) {
    s  += __shfl_xor(s, off);
    s2 += __shfl_xor(s2, off);
  }
  __shared__ float red[8];
  const int wave = t >> 6, lane = t & 63;
  if (lane == 0) { red[wave] = s; red[wave + 4] = s2; }
  __syncthreads();
  float ts  = red[0] + red[1] + red[2] + red[3];
  float ts2 = red[4] + red[5] + red[6] + red[7];
  float mu  = ts * (1.f / 1024.f);
  float var = ts2 * (1.f / 1024.f) - mu * mu;
  float rs  = rsqrtf(var + 1e-5f);
  floatx4 gv = ((const floatx4*)g)[t];
  floatx4 bev = ((const floatx4*)be)[t];
  ushort4 ov;
  ov.x = f32_to_bf16((v[0] - mu) * rs * gv[0] + bev[0]);
  ov.y = f32_to_bf16((v[1] - mu) * rs * gv[1] + bev[1]);
  ov.z = f32_to_bf16((v[2] - mu) * rs * gv[2] + bev[2]);
  ov.w = f32_to_bf16((v[3] - mu) * rs * gv[3] + bev[3]);
  ((ushort4*)(nxout + (size_t)row * 1024))[t] = ov;
}

// ---------------- MFMA flash attention, causal ------------------------------
// 128 q-rows/block, 4 waves x 32 rows. Fixed-base softmax (p=exp(S)). LDS
// stride 68 halfs: 52.2 KB -> 3 blocks/CU. XCD-colocated block mapping;
// raw s_barrier with lgkmcnt(0) only (prefetch spans barrier); setprio.
__global__ __launch_bounds__(256, 3) void flash_attn_mfma(
    const unsigned short* __restrict__ qkv,
    const unsigned short* __restrict__ vT,
    unsigned short* __restrict__ attn) {
  const int id = blockIdx.x;
  const int xcd = id & 7, slot = id >> 3;      // 64 slots per XCD class
  const int bh = xcd * 4 + (slot & 3);         // 4 (b,h) pairs per XCD
  const int qt = 15 - (slot >> 2);             // biggest first
  const int b = bh >> 4, h = bh & 15;
  const int q0 = qt * 128;
  const int t = threadIdx.x;
  const int wave = t >> 6, lane = t & 63;
  const int l15 = lane & 15, quad = lane >> 4;

  __shared__ unsigned short Ks[2][64][68];   // [buf][key][d]
  __shared__ unsigned short Vs[2][64][68];   // [buf][d][key]
  __shared__ unsigned short Ps[4][32][68];   // per-wave P [q][key]

  const size_t qbase = (size_t)b * 2048 * 3072;
  const int qrow_w = q0 + wave * 32;
  const unsigned short* Kbase = qkv + qbase + 1024 + h * 64;  // stride 3072
  const unsigned short* Vbase = vT + (size_t)bh * 64 * 2048;  // stride 2048

  // Q frags (rows mf*16+l15, scaled by 1/8 exactly)
  short8 qf[2][2];
#pragma unroll
  for (int mf = 0; mf < 2; ++mf)
#pragma unroll
    for (int kc = 0; kc < 2; ++kc) {
      short8 raw = *(const short8*)(qkv + qbase +
          (size_t)(qrow_w + mf * 16 + l15) * 3072 + h * 64 + kc * 32 + quad * 8);
      short8 sc;
#pragma unroll
      for (int j = 0; j < 8; ++j)
        sc[j] = (short)f32_to_bf16(bf16_to_f32((unsigned short)raw[j]) * 0.125f);
      qf[mf][kc] = sc;
    }

  floatx4 o[2][4];
  float l_s[2] = {0.f, 0.f};  // per-lane partial row-sum for q = mf*16+l15
#pragma unroll
  for (int mf = 0; mf < 2; ++mf)
#pragma unroll
    for (int jd = 0; jd < 4; ++jd) o[mf][jd] = floatx4{0.f, 0.f, 0.f, 0.f};

  const int sr = t >> 3, so = (t & 7) * 8;  // staging rows sr, sr+32

  // prefetch tile 0
  uint4 kr0 = *(const uint4*)(Kbase + (size_t)sr * 3072 + so);
  uint4 kr1 = *(const uint4*)(Kbase + (size_t)(sr + 32) * 3072 + so);
  uint4 vr0 = *(const uint4*)(Vbase + (size_t)sr * 2048 + so);
  uint4 vr1 = *(const uint4*)(Vbase + (size_t)(sr + 32) * 2048 + so);

  const int ntiles = 2 * qt + 2;
  int buf = 0;
  for (int kt = 0; kt < ntiles; ++kt) {
    const int k0 = kt * 64;
    *(uint4*)&Ks[buf][sr][so]      = kr0;
    *(uint4*)&Ks[buf][sr + 32][so] = kr1;
    *(uint4*)&Vs[buf][sr][so]      = vr0;
    *(uint4*)&Vs[buf][sr + 32][so] = vr1;
    if (kt + 1 < ntiles) {
      const int k1 = k0 + 64;
      kr0 = *(const uint4*)(Kbase + (size_t)(k1 + sr) * 3072 + so);
      kr1 = *(const uint4*)(Kbase + (size_t)(k1 + sr + 32) * 3072 + so);
      vr0 = *(const uint4*)(Vbase + (size_t)sr * 2048 + k1 + so);
      vr1 = *(const uint4*)(Vbase + (size_t)(sr + 32) * 2048 + k1 + so);
    }
    asm volatile("s_waitcnt lgkmcnt(0)" ::: "memory");  // LDS writes visible
    __builtin_amdgcn_s_barrier();

    if (k0 <= qrow_w + 31) {  // wave-uniform skip of all-masked tiles
      short8 kf[2][4];
#pragma unroll
      for (int kc = 0; kc < 2; ++kc)
#pragma unroll
        for (int jb = 0; jb < 4; ++jb)
          kf[kc][jb] = *(const short8*)&Ks[buf][jb * 16 + l15][kc * 32 + quad * 8];

      // S^T: st[mf][jb] : D[row=key=jb*16+quad*4+r][col=q=mf*16+l15]
      floatx4 st[2][4];
#pragma unroll
      for (int mf = 0; mf < 2; ++mf)
#pragma unroll
        for (int jb = 0; jb < 4; ++jb) st[mf][jb] = floatx4{0.f, 0.f, 0.f, 0.f};
      __builtin_amdgcn_s_setprio(1);
#pragma unroll
      for (int kc = 0; kc < 2; ++kc)
#pragma unroll
        for (int jb = 0; jb < 4; ++jb) {
#pragma unroll
          for (int mf = 0; mf < 2; ++mf)
            st[mf][jb] = __builtin_amdgcn_mfma_f32_16x16x32_bf16(
                kf[kc][jb], qf[mf][kc], st[mf][jb], 0, 0, 0);
        }
      __builtin_amdgcn_s_setprio(0);

      // exp + causal mask + l accumulation + pack to Ps (b64 per (mf,jb))
#pragma unroll
      for (int mf = 0; mf < 2; ++mf) {
        const int qq = qrow_w + mf * 16 + l15;
#pragma unroll
        for (int jb = 0; jb < 4; ++jb) {
          const int keyb = k0 + jb * 16 + quad * 4;
          float p0 = (keyb + 0 > qq) ? 0.f : __expf(st[mf][jb][0]);
          float p1 = (keyb + 1 > qq) ? 0.f : __expf(st[mf][jb][1]);
          float p2 = (keyb + 2 > qq) ? 0.f : __expf(st[mf][jb][2]);
          float p3 = (keyb + 3 > qq) ? 0.f : __expf(st[mf][jb][3]);
          l_s[mf] += (p0 + p1) + (p2 + p3);
          uint2 pk;
          pk.x = (f32_to_bf16_hi(p1) << 16) | f32_to_bf16_hi(p0);
          pk.y = (f32_to_bf16_hi(p3) << 16) | f32_to_bf16_hi(p2);
          *(uint2*)&Ps[wave][mf * 16 + l15][jb * 16 + quad * 4] = pk;
        }
      }

      // O += P V : 16 MFMAs
      __builtin_amdgcn_s_setprio(1);
#pragma unroll
      for (int kc = 0; kc < 2; ++kc) {
        short8 pf0 = *(const short8*)&Ps[wave][l15][kc * 32 + quad * 8];
        short8 pf1 = *(const short8*)&Ps[wave][16 + l15][kc * 32 + quad * 8];
#pragma unroll
        for (int jd = 0; jd < 4; ++jd) {
          short8 vf = *(const short8*)&Vs[buf][jd * 16 + l15][kc * 32 + quad * 8];
          o[0][jd] = __builtin_amdgcn_mfma_f32_16x16x32_bf16(pf0, vf, o[0][jd], 0, 0, 0);
          o[1][jd] = __builtin_amdgcn_mfma_f32_16x16x32_bf16(pf1, vf, o[1][jd], 0, 0, 0);
        }
      }
      __builtin_amdgcn_s_setprio(0);
    }
    buf ^= 1;
  }

  // final l reduce across the 4 quads holding the same l15
#pragma unroll
  for (int mf = 0; mf < 2; ++mf) {
    l_s[mf] += __shfl_xor(l_s[mf], 16);
    l_s[mf] += __shfl_xor(l_s[mf], 32);
  }

  // epilogue: o row q = mf*16 + quad*4 + r; l for that q lives at lane (quad*4+r)
#pragma unroll
  for (int mf = 0; mf < 2; ++mf)
#pragma unroll
    for (int r = 0; r < 4; ++r) {
      const int qloc = quad * 4 + r;
      const float lsum = __shfl(l_s[mf], qloc);
      const float rl = 1.f / lsum;
      const int row = b * 2048 + q0 + wave * 32 + mf * 16 + qloc;
#pragma unroll
      for (int jd = 0; jd < 4; ++jd)
        attn[(size_t)row * 1024 + h * 64 + jd * 16 + l15] =
            f32_to_bf16(o[mf][jd][r] * rl);
    }
}

// ---------------------------------------------------------------------------
extern "C" void kernel_launch(void* const* d_in, const int* in_sizes, int n_in,
                              void* d_out, int out_size, void* d_ws, size_t ws_size,
                              hipStream_t stream) {
  const float* x   = (const float*)d_in[0];
  const float* Wq  = (const float*)d_in[1];
  const float* Wk  = (const float*)d_in[2];
  const float* Wv  = (const float*)d_in[3];
  const float* Wo  = (const float*)d_in[4];
  const float* bo  = (const float*)d_in[5];
  const float* W1  = (const float*)d_in[6];
  const float* b1  = (const float*)d_in[7];
  const float* W2  = (const float*)d_in[8];
  const float* b2  = (const float*)d_in[9];
  const float* g1  = (const float*)d_in[10];
  const float* be1 = (const float*)d_in[11];
  const float* g2  = (const float*)d_in[12];
  const float* be2 = (const float*)d_in[13];
  float* out = (float*)d_out;

  char* ws = (char*)d_ws;
  size_t off = 0;
  auto alloc = [&](size_t bytes) -> void* {
    void* p = ws + off;
    off += (bytes + 255) & ~(size_t)255;
    return p;
  };
  unsigned short* WqkvT = (unsigned short*)alloc(3072ull * 1024 * 2);
  unsigned short* WoT   = (unsigned short*)alloc(1024ull * 1024 * 2);
  unsigned short* W1T   = (unsigned short*)alloc(4096ull * 1024 * 2);
  unsigned short* W2T   = (unsigned short*)alloc(1024ull * 4096 * 2);
  unsigned short* nx    = (unsigned short*)alloc(4096ull * 1024 * 2);   // 8 MB
  unsigned short* qkv   = (unsigned short*)alloc(4096ull * 3072 * 2);   // 24 MB
  unsigned short* attn  = (unsigned short*)alloc(4096ull * 1024 * 2);
  float*          x1    = (float*)alloc(4096ull * 1024 * 4);
  unsigned short* nx2   = (unsigned short*)alloc(4096ull * 1024 * 2);
  unsigned short* hbuf  = (unsigned short*)alloc(4096ull * 4096 * 2);
  // vT (8 MB) aliases hbuf: vT dead before GEMM3 writes hbuf
  unsigned short* vT    = hbuf;
  // split-K fp32 partials (2 x 16 MB) alias nx+qkv (both dead when used:
  // nx dead after GEMM1; qkv dead after flash; region = exactly 32 MB)
  float*          part  = (float*)nx;

  dim3 blk(256);
  // all four weight transposes in ONE launch (12288 blocks)
  transpose_weights_all<<<dim3(12288), blk, 0, stream>>>(
      Wq, Wk, Wv, Wo, W1, W2, WqkvT, WoT, W1T, W2T);

  layernorm_bf16<<<4096, blk, 0, stream>>>(x, g1, be1, nx);
  // GEMM1: 4096x3072x1024 -> bf16 qkv  (2D XCD map: 8m x 12n per XCD)
  gemm_bf16<<<dim3(24, 32, 1), blk, 0, stream>>>(nx, WqkvT, nullptr, nullptr, qkv, 4096, 3072, 1024, 1024, 0, 4);
  transpose_v<<<dim3(64, 2, 32), blk, 0, stream>>>(qkv, vT);
  flash_attn_mfma<<<dim3(512, 1, 1), blk, 0, stream>>>(qkv, vT, attn);
  // GEMM2 split-K=2 (fp32 partials) -> fused reduce+LN  (legacy map, L2-fit)
  gemm_bf16<<<dim3(8, 32, 2), blk, 0, stream>>>(attn, WoT, nullptr, nullptr, part, 4096, 1024, 1024, 512, 3, 8);
  splitk_reduce_ln<<<4096, blk, 0, stream>>>(part, bo, x, g2, be2, x1, nx2);
  // GEMM3: 4096x4096x1024 relu+bias -> bf16 hbuf  (2D XCD map: 8m x 16n per XCD)
  gemm_bf16<<<dim3(32, 32, 1), blk, 0, stream>>>(nx2, W1T, b1, nullptr, hbuf, 4096, 4096, 1024, 1024, 2, 4);
  // GEMM4 split-K=2 (fp32 partials) -> reduce  (legacy map, L2-fit)
  gemm_bf16<<<dim3(8, 32, 2), blk, 0, stream>>>(hbuf, W2T, nullptr, nullptr, part, 4096, 1024, 4096, 2048, 3, 8);
  splitk_reduce<<<4096, blk, 0, stream>>>(part, b2, x1, out);
}

// Round 17
// 350.097 us; speedup vs baseline: 1.0200x; 1.0013x over previous
//
#include <hip/hip_runtime.h>

// B=2, S=2048, E=1024, H=16, DH=64, FF=4096.  All dims hardcoded.
// R25: R24 + transpose_v ELIMINATED: GEMM1's mode-0 epilogue writes the V
//      n-panels (n0>=2048) directly into vT's transposed layout from the
//      LDS-staged C tile (vT[(b*1024+hd)*2048+k] = C[b*2048+k][2048+hd]).
//      Saves the 16 MB transpose_v pass + launch. qkv's V columns are dead
//      (flash reads only Q/K). Everything else identical to R24.

typedef __attribute__((ext_vector_type(8))) short short8;
typedef __attribute__((ext_vector_type(4))) float floatx4;

__device__ inline unsigned short f32_to_bf16(float f) {
  unsigned u = __float_as_uint(f);
  unsigned rb = (u >> 16) & 1u;  // round-to-nearest-even
  u += 0x7fffu + rb;
  return (unsigned short)(u >> 16);
}
__device__ inline unsigned f32_to_bf16_hi(float f) {  // round-half-up, cheap
  return (__float_as_uint(f) + 0x8000u) >> 16;
}
__device__ inline float bf16_to_f32(unsigned short u) {
  return __uint_as_float(((unsigned)u) << 16);
}

// async global -> LDS, 16 bytes per lane. LDS dest = wave-uniform base + lane*16.
__device__ inline void gload16(const void* g, void* l) {
  __builtin_amdgcn_global_load_lds(
      (const __attribute__((address_space(1))) void*)g,
      (__attribute__((address_space(3))) void*)l, 16, 0, 0);
}

// ---------------- ALL weight transposes, one launch: fp32 -> bf16 ----------
// flat grid 12288 blocks of 256:
//   [0,3072):  Wq/Wk/Wv  per z in [0,48): in (z&15)*65536 of mat z>>4,
//              C=64, ldo=1024, 64 blocks/z (2 x 32)
//   [3072,4096): Wo  1024x1024 -> 1024x1024   (32 x 32)
//   [4096,8192): W1  1024x4096 -> 4096x1024   (128 x 32)
//   [8192,12288): W2 4096x1024 -> 1024x4096   (32 x 128)
__global__ __launch_bounds__(256) void transpose_weights_all(
    const float* __restrict__ Wq, const float* __restrict__ Wk,
    const float* __restrict__ Wv, const float* __restrict__ Wo,
    const float* __restrict__ W1, const float* __restrict__ W2,
    unsigned short* __restrict__ WqkvT, unsigned short* __restrict__ WoT,
    unsigned short* __restrict__ W1T, unsigned short* __restrict__ W2T) {
  __shared__ float tile[32][33];
  const int b = blockIdx.x;
  const float* in;
  unsigned short* out;
  int C, ldo, c0, r0;
  if (b < 3072) {
    const int z = b >> 6, rem = b & 63, m = z >> 4;
    in  = (m == 0 ? Wq : (m == 1 ? Wk : Wv)) + (size_t)(z & 15) * 65536;
    out = WqkvT + (size_t)z * 65536;
    C = 64; ldo = 1024;
    c0 = (rem & 1) * 32; r0 = (rem >> 1) * 32;
  } else if (b < 4096) {
    const int idx = b - 3072;
    in = Wo; out = WoT; C = 1024; ldo = 1024;
    c0 = (idx & 31) * 32; r0 = (idx >> 5) * 32;
  } else if (b < 8192) {
    const int idx = b - 4096;
    in = W1; out = W1T; C = 4096; ldo = 1024;
    c0 = (idx & 127) * 32; r0 = (idx >> 7) * 32;
  } else {
    const int idx = b - 8192;
    in = W2; out = W2T; C = 1024; ldo = 4096;
    c0 = (idx & 31) * 32; r0 = (idx >> 5) * 32;
  }
  const int tx = threadIdx.x & 31, ty = threadIdx.x >> 5;
#pragma unroll
  for (int i = 0; i < 32; i += 8)
    tile[ty + i][tx] = in[(size_t)(r0 + ty + i) * C + c0 + tx];
  __syncthreads();
#pragma unroll
  for (int i = 0; i < 32; i += 8)
    out[(size_t)(c0 + ty + i) * ldo + r0 + tx] = f32_to_bf16(tile[tx][ty + i]);
}

// ---------------- LayerNorm: fp32 [rows][1024] -> bf16, one block per row ---
__global__ __launch_bounds__(256) void layernorm_bf16(
    const float* __restrict__ x, const float* __restrict__ g,
    const float* __restrict__ be, unsigned short* __restrict__ out) {
  const int row = blockIdx.x;
  const int t = threadIdx.x;
  floatx4 v = ((const floatx4*)(x + (size_t)row * 1024))[t];
  float s  = v[0] + v[1] + v[2] + v[3];
  float s2 = v[0]*v[0] + v[1]*v[1] + v[2]*v[2] + v[3]*v[3];
#pragma unroll
  for (int off = 1; off < 64; off <<= 1) {
    s  += __shfl_xor(s, off);
    s2 += __shfl_xor(s2, off);
  }
  __shared__ float red[8];
  const int wave = t >> 6, lane = t & 63;
  if (lane == 0) { red[wave] = s; red[wave + 4] = s2; }
  __syncthreads();
  float ts  = red[0] + red[1] + red[2] + red[3];
  float ts2 = red[4] + red[5] + red[6] + red[7];
  float mu  = ts * (1.f / 1024.f);
  float var = ts2 * (1.f / 1024.f) - mu * mu;
  float rs  = rsqrtf(var + 1e-5f);
  floatx4 gv = ((const floatx4*)g)[t];
  floatx4 bv = ((const floatx4*)be)[t];
  ushort4 ov;
  ov.x = f32_to_bf16((v[0] - mu) * rs * gv[0] + bv[0]);
  ov.y = f32_to_bf16((v[1] - mu) * rs * gv[1] + bv[1]);
  ov.z = f32_to_bf16((v[2] - mu) * rs * gv[2] + bv[2]);
  ov.w = f32_to_bf16((v[3] - mu) * rs * gv[3] + bv[3]);
  ((ushort4*)(out + (size_t)row * 1024))[t] = ov;
}

// ---------------- bf16 MFMA GEMM: C = A[M,Kfull sub Klen] @ Bt^T ------------
// dbuf LDS [2][128][32] linear, global_load_lds width 16, stage-ahead with
// counted vmcnt(4): next tile's 4 DMA loads stay in flight across barrier #1.
// 2D XCD mapping (XA = XCDs along m); XA=8 == legacy strip exactly.
// blockIdx.z = split-K slice (offset z*Klen into K).
// mode 0: bf16 store; 1: fp32 +bias+resid; 2: bf16 relu(+bias); 3: fp32 partial
// bf16 modes (0/2) stage the C tile through LDS, coalesced uint4 stores.
// mode 0 with vTout != nullptr: tiles with n0 >= 2048 (the V section of the
// qkv GEMM) are stored TRANSPOSED into vT[(b*1024+hd)*2048 + k] instead of
// Cout (fuses the old transpose_v kernel; qkv V columns stay unwritten/dead).
__global__ __launch_bounds__(256, 4) void gemm_bf16(
    const unsigned short* __restrict__ A, const unsigned short* __restrict__ Bt,
    const float* __restrict__ bias, const float* __restrict__ resid,
    void* __restrict__ Cout, unsigned short* __restrict__ vTout,
    int M, int N, int Kfull, int Klen, int mode, int XA) {
  __shared__ unsigned short As[2][128 * 32];
  __shared__ unsigned short Bs[2][128 * 32];
  const int t = threadIdx.x;
  const int NB = gridDim.x;  // n-panels; gridDim.y * 128 == M
  const int bid = blockIdx.y * NB + blockIdx.x;
  const int xcd = bid & 7, s = bid >> 3;
  const int mx = (M >> 7) / XA;          // m-panels per XCD
  const int nxp = (NB * XA) >> 3;        // n-panels per XCD
  const int xcd_m = xcd % XA, xcd_n = xcd / XA;
  const int m0 = (xcd_m * mx + s / nxp) * 128;
  const int n0 = (xcd_n * nxp + s % nxp) * 128;
  const int koff = blockIdx.z * Klen;
  const int lane = t & 63, wave = t >> 6;
  const int wm = (wave >> 1) * 64, wn = (wave & 1) * 64;
  const int l15 = lane & 15, quad = lane >> 4;

  floatx4 acc[4][4];
#pragma unroll
  for (int i = 0; i < 4; ++i)
#pragma unroll
    for (int j = 0; j < 4; ++j) acc[i][j] = floatx4{0.f, 0.f, 0.f, 0.f};

  const int srow = wave * 32 + (lane >> 2);
  const int scol = (lane & 3) * 8;
  const unsigned short* Ag0 = A + (size_t)(m0 + srow) * Kfull + koff + scol;
  const unsigned short* Ag1 = Ag0 + (size_t)16 * Kfull;
  const unsigned short* Bg0 = Bt + (size_t)(n0 + srow) * Kfull + koff + scol;
  const unsigned short* Bg1 = Bg0 + (size_t)16 * Kfull;
  const int sbase0 = (wave * 2 + 0) * 512;
  const int sbase1 = (wave * 2 + 1) * 512;

  const int KT = Klen >> 5;
  gload16(Ag0, &As[0][sbase0]);
  gload16(Ag1, &As[0][sbase1]);
  gload16(Bg0, &Bs[0][sbase0]);
  gload16(Bg1, &Bs[0][sbase1]);

  int buf = 0;
  for (int kt = 0; kt < KT; ++kt) {
    if (kt + 1 < KT) {
      const int ko = (kt + 1) * 32;
      gload16(Ag0 + ko, &As[buf ^ 1][sbase0]);
      gload16(Ag1 + ko, &As[buf ^ 1][sbase1]);
      gload16(Bg0 + ko, &Bs[buf ^ 1][sbase0]);
      gload16(Bg1 + ko, &Bs[buf ^ 1][sbase1]);
      asm volatile("s_waitcnt vmcnt(4)" ::: "memory");
    } else {
      asm volatile("s_waitcnt vmcnt(0)" ::: "memory");
    }
    __builtin_amdgcn_s_barrier();
    short8 a[4], b[4];
#pragma unroll
    for (int i = 0; i < 4; ++i)
      a[i] = *(const short8*)&As[buf][(wm + i * 16 + l15) * 32 + quad * 8];
#pragma unroll
    for (int i = 0; i < 4; ++i)
      b[i] = *(const short8*)&Bs[buf][(wn + i * 16 + l15) * 32 + quad * 8];
#pragma unroll
    for (int i = 0; i < 4; ++i)
#pragma unroll
      for (int j = 0; j < 4; ++j)
        acc[i][j] = __builtin_amdgcn_mfma_f32_16x16x32_bf16(a[i], b[j], acc[i][j], 0, 0, 0);
    __builtin_amdgcn_s_barrier();
    buf ^= 1;
  }
  __builtin_amdgcn_sched_barrier(0);

  if (mode == 0 || mode == 2) {
    // ---- coalesced bf16 epilogue: stage C half-tiles (64x128, 16 KB) in As.
    unsigned short* Cs = &As[0][0];  // 8192 halfs
    const bool vtile = (vTout != nullptr) && (n0 >= 2048);
#pragma unroll
    for (int p = 0; p < 2; ++p) {
      if ((wm >> 6) == p) {  // waves owning rows [p*64, p*64+64)
#pragma unroll
        for (int i = 0; i < 4; ++i)
#pragma unroll
          for (int j = 0; j < 4; ++j)
#pragma unroll
            for (int r = 0; r < 4; ++r) {
              const int rl = i * 16 + quad * 4 + r;       // 0..63 within half
              float v = acc[i][j][r];
              if (mode == 2) {
                v += bias[n0 + wn + j * 16 + l15];
                v = fmaxf(v, 0.f);
              }
              Cs[rl * 128 + wn + j * 16 + l15] = f32_to_bf16(v);
            }
      }
      __syncthreads();
      if (vtile) {
        // V section: store transposed into vT[(b*1024+hd)*2048 + k].
        // Block rows never straddle the 2048 b-boundary (m0, 2048 both
        // multiples of 128), so b and the k-base are uniform per block.
        const int b_  = m0 >> 11;
        const int k0_ = (m0 & 2047) + p * 64;
#pragma unroll
        for (int c4 = 0; c4 < 4; ++c4) {
          const int idx = c4 * 256 + t;   // 0..1023
          const int col = idx >> 3;       // 0..127 (local column)
          const int rb_ = (idx & 7) * 8;  // row-chunk base 0..56
          const int hd  = n0 - 2048 + col;  // head*64 + d
          unsigned short tmp[8];
#pragma unroll
          for (int j = 0; j < 8; ++j) tmp[j] = Cs[(rb_ + j) * 128 + col];
          *(uint4*)&vTout[((size_t)(b_ * 1024) + hd) * 2048 + k0_ + rb_] =
              *(const uint4*)tmp;
        }
      } else {
        // store 16 KB as 1024 uint4 chunks: full 64B lines, coalesced
#pragma unroll
        for (int c = 0; c < 4; ++c) {
          const int idx = c * 256 + t;          // 0..1023
          const int row = idx >> 4, chunk = idx & 15;
          *(uint4*)&((unsigned short*)Cout)[(size_t)(m0 + p * 64 + row) * N + n0 + chunk * 8] =
              *(const uint4*)&Cs[row * 128 + chunk * 8];
        }
      }
      __syncthreads();
    }
  } else {
    const size_t poff = (size_t)blockIdx.z * 4096 * 1024;  // partial slab
#pragma unroll
    for (int i = 0; i < 4; ++i)
#pragma unroll
      for (int j = 0; j < 4; ++j) {
        const int col = n0 + wn + j * 16 + l15;
        const int rb = m0 + wm + i * 16 + quad * 4;
#pragma unroll
        for (int r = 0; r < 4; ++r) {
          const int row = rb + r;
          float v = acc[i][j][r];
          if (mode == 1) {
            v += bias[col] + resid[(size_t)row * N + col];
            ((float*)Cout)[(size_t)row * N + col] = v;
          } else {
            ((float*)Cout)[poff + (size_t)row * N + col] = v;
          }
        }
      }
  }
}

// ---------------- split-K reduce: out = p0 + p1 + bias + resid  (N=1024) ----
__global__ __launch_bounds__(256) void splitk_reduce(
    const float* __restrict__ p, const float* __restrict__ bias,
    const float* __restrict__ resid, float* __restrict__ out) {
  const int t = threadIdx.x;                  // 256 float4 per row
  const size_t base = (size_t)blockIdx.x * 256 + t;
  floatx4 a = ((const floatx4*)p)[base];
  floatx4 b = ((const floatx4*)p)[1048576 + base];  // + M*N/4
  floatx4 rv = ((const floatx4*)resid)[base];
  floatx4 bv = ((const floatx4*)bias)[t];
  ((floatx4*)out)[base] = a + b + rv + bv;
}

// ---------------- fused split-K=2 reduce + LayerNorm (GEMM2 -> x1 -> nx2) ---
__global__ __launch_bounds__(256) void splitk_reduce_ln(
    const float* __restrict__ p, const float* __restrict__ bias,
    const float* __restrict__ resid, const float* __restrict__ g,
    const float* __restrict__ be, float* __restrict__ xout,
    unsigned short* __restrict__ nxout) {
  const int row = blockIdx.x, t = threadIdx.x;
  const size_t base = (size_t)row * 256 + t;
  floatx4 a = ((const floatx4*)p)[base];
  floatx4 b = ((const floatx4*)p)[1048576 + base];  // + M*N/4
  floatx4 rv = ((const floatx4*)resid)[base];
  floatx4 bv = ((const floatx4*)bias)[t];
  floatx4 v = a + b + rv + bv;
  ((floatx4*)xout)[base] = v;
  float s  = v[0] + v[1] + v[2] + v[3];
  float s2 = v[0]*v[0] + v[1]*v[1] + v[2]*v[2] + v[3]*v[3];
#pragma unroll
  for (int off = 1; off < 64; off <<= 1) {
    s  += __shfl_xor(s, off);
    s2 += __shfl_xor(s2, off);
  }
  __shared__ float red[8];
  const int wave = t >> 6, lane = t & 63;
  if (lane == 0) { red[wave] = s; red[wave + 4] = s2; }
  __syncthreads();
  float ts  = red[0] + red[1] + red[2] + red[3];
  float ts2 = red[4] + red[5] + red[6] + red[7];
  float mu  = ts * (1.f / 1024.f);
  float var = ts2 * (1.f / 1024.f) - mu * mu;
  float rs  = rsqrtf(var + 1e-5f);
  floatx4 gv = ((const floatx4*)g)[t];
  floatx4 bev = ((const floatx4*)be)[t];
  ushort4 ov;
  ov.x = f32_to_bf16((v[0] - mu) * rs * gv[0] + bev[0]);
  ov.y = f32_to_bf16((v[1] - mu) * rs * gv[1] + bev[1]);
  ov.z = f32_to_bf16((v[2] - mu) * rs * gv[2] + bev[2]);
  ov.w = f32_to_bf16((v[3] - mu) * rs * gv[3] + bev[3]);
  ((ushort4*)(nxout + (size_t)row * 1024))[t] = ov;
}

// ---------------- MFMA flash attention, causal ------------------------------
// 128 q-rows/block, 4 waves x 32 rows. Fixed-base softmax (p=exp(S)). LDS
// stride 68 halfs: 52.2 KB -> 3 blocks/CU. XCD-colocated block mapping;
// raw s_barrier with lgkmcnt(0) only (prefetch spans barrier); setprio.
__global__ __launch_bounds__(256, 3) void flash_attn_mfma(
    const unsigned short* __restrict__ qkv,
    const unsigned short* __restrict__ vT,
    unsigned short* __restrict__ attn) {
  const int id = blockIdx.x;
  const int xcd = id & 7, slot = id >> 3;      // 64 slots per XCD class
  const int bh = xcd * 4 + (slot & 3);         // 4 (b,h) pairs per XCD
  const int qt = 15 - (slot >> 2);             // biggest first
  const int b = bh >> 4, h = bh & 15;
  const int q0 = qt * 128;
  const int t = threadIdx.x;
  const int wave = t >> 6, lane = t & 63;
  const int l15 = lane & 15, quad = lane >> 4;

  __shared__ unsigned short Ks[2][64][68];   // [buf][key][d]
  __shared__ unsigned short Vs[2][64][68];   // [buf][d][key]
  __shared__ unsigned short Ps[4][32][68];   // per-wave P [q][key]

  const size_t qbase = (size_t)b * 2048 * 3072;
  const int qrow_w = q0 + wave * 32;
  const unsigned short* Kbase = qkv + qbase + 1024 + h * 64;  // stride 3072
  const unsigned short* Vbase = vT + (size_t)bh * 64 * 2048;  // stride 2048

  // Q frags (rows mf*16+l15, scaled by 1/8 exactly)
  short8 qf[2][2];
#pragma unroll
  for (int mf = 0; mf < 2; ++mf)
#pragma unroll
    for (int kc = 0; kc < 2; ++kc) {
      short8 raw = *(const short8*)(qkv + qbase +
          (size_t)(qrow_w + mf * 16 + l15) * 3072 + h * 64 + kc * 32 + quad * 8);
      short8 sc;
#pragma unroll
      for (int j = 0; j < 8; ++j)
        sc[j] = (short)f32_to_bf16(bf16_to_f32((unsigned short)raw[j]) * 0.125f);
      qf[mf][kc] = sc;
    }

  floatx4 o[2][4];
  float l_s[2] = {0.f, 0.f};  // per-lane partial row-sum for q = mf*16+l15
#pragma unroll
  for (int mf = 0; mf < 2; ++mf)
#pragma unroll
    for (int jd = 0; jd < 4; ++jd) o[mf][jd] = floatx4{0.f, 0.f, 0.f, 0.f};

  const int sr = t >> 3, so = (t & 7) * 8;  // staging rows sr, sr+32

  // prefetch tile 0
  uint4 kr0 = *(const uint4*)(Kbase + (size_t)sr * 3072 + so);
  uint4 kr1 = *(const uint4*)(Kbase + (size_t)(sr + 32) * 3072 + so);
  uint4 vr0 = *(const uint4*)(Vbase + (size_t)sr * 2048 + so);
  uint4 vr1 = *(const uint4*)(Vbase + (size_t)(sr + 32) * 2048 + so);

  const int ntiles = 2 * qt + 2;
  int buf = 0;
  for (int kt = 0; kt < ntiles; ++kt) {
    const int k0 = kt * 64;
    *(uint4*)&Ks[buf][sr][so]      = kr0;
    *(uint4*)&Ks[buf][sr + 32][so] = kr1;
    *(uint4*)&Vs[buf][sr][so]      = vr0;
    *(uint4*)&Vs[buf][sr + 32][so] = vr1;
    if (kt + 1 < ntiles) {
      const int k1 = k0 + 64;
      kr0 = *(const uint4*)(Kbase + (size_t)(k1 + sr) * 3072 + so);
      kr1 = *(const uint4*)(Kbase + (size_t)(k1 + sr + 32) * 3072 + so);
      vr0 = *(const uint4*)(Vbase + (size_t)sr * 2048 + k1 + so);
      vr1 = *(const uint4*)(Vbase + (size_t)(sr + 32) * 2048 + k1 + so);
    }
    asm volatile("s_waitcnt lgkmcnt(0)" ::: "memory");  // LDS writes visible
    __builtin_amdgcn_s_barrier();

    if (k0 <= qrow_w + 31) {  // wave-uniform skip of all-masked tiles
      short8 kf[2][4];
#pragma unroll
      for (int kc = 0; kc < 2; ++kc)
#pragma unroll
        for (int jb = 0; jb < 4; ++jb)
          kf[kc][jb] = *(const short8*)&Ks[buf][jb * 16 + l15][kc * 32 + quad * 8];

      // S^T: st[mf][jb] : D[row=key=jb*16+quad*4+r][col=q=mf*16+l15]
      floatx4 st[2][4];
#pragma unroll
      for (int mf = 0; mf < 2; ++mf)
#pragma unroll
        for (int jb = 0; jb < 4; ++jb) st[mf][jb] = floatx4{0.f, 0.f, 0.f, 0.f};
      __builtin_amdgcn_s_setprio(1);
#pragma unroll
      for (int kc = 0; kc < 2; ++kc)
#pragma unroll
        for (int jb = 0; jb < 4; ++jb) {
#pragma unroll
          for (int mf = 0; mf < 2; ++mf)
            st[mf][jb] = __builtin_amdgcn_mfma_f32_16x16x32_bf16(
                kf[kc][jb], qf[mf][kc], st[mf][jb], 0, 0, 0);
        }
      __builtin_amdgcn_s_setprio(0);

      // exp + causal mask + l accumulation + pack to Ps (b64 per (mf,jb))
#pragma unroll
      for (int mf = 0; mf < 2; ++mf) {
        const int qq = qrow_w + mf * 16 + l15;
#pragma unroll
        for (int jb = 0; jb < 4; ++jb) {
          const int keyb = k0 + jb * 16 + quad * 4;
          float p0 = (keyb + 0 > qq) ? 0.f : __expf(st[mf][jb][0]);
          float p1 = (keyb + 1 > qq) ? 0.f : __expf(st[mf][jb][1]);
          float p2 = (keyb + 2 > qq) ? 0.f : __expf(st[mf][jb][2]);
          float p3 = (keyb + 3 > qq) ? 0.f : __expf(st[mf][jb][3]);
          l_s[mf] += (p0 + p1) + (p2 + p3);
          uint2 pk;
          pk.x = (f32_to_bf16_hi(p1) << 16) | f32_to_bf16_hi(p0);
          pk.y = (f32_to_bf16_hi(p3) << 16) | f32_to_bf16_hi(p2);
          *(uint2*)&Ps[wave][mf * 16 + l15][jb * 16 + quad * 4] = pk;
        }
      }

      // O += P V : 16 MFMAs
      __builtin_amdgcn_s_setprio(1);
#pragma unroll
      for (int kc = 0; kc < 2; ++kc) {
        short8 pf0 = *(const short8*)&Ps[wave][l15][kc * 32 + quad * 8];
        short8 pf1 = *(const short8*)&Ps[wave][16 + l15][kc * 32 + quad * 8];
#pragma unroll
        for (int jd = 0; jd < 4; ++jd) {
          short8 vf = *(const short8*)&Vs[buf][jd * 16 + l15][kc * 32 + quad * 8];
          o[0][jd] = __builtin_amdgcn_mfma_f32_16x16x32_bf16(pf0, vf, o[0][jd], 0, 0, 0);
          o[1][jd] = __builtin_amdgcn_mfma_f32_16x16x32_bf16(pf1, vf, o[1][jd], 0, 0, 0);
        }
      }
      __builtin_amdgcn_s_setprio(0);
    }
    buf ^= 1;
  }

  // final l reduce across the 4 quads holding the same l15
#pragma unroll
  for (int mf = 0; mf < 2; ++mf) {
    l_s[mf] += __shfl_xor(l_s[mf], 16);
    l_s[mf] += __shfl_xor(l_s[mf], 32);
  }

  // epilogue: o row q = mf*16 + quad*4 + r; l for that q lives at lane (quad*4+r)
#pragma unroll
  for (int mf = 0; mf < 2; ++mf)
#pragma unroll
    for (int r = 0; r < 4; ++r) {
      const int qloc = quad * 4 + r;
      const float lsum = __shfl(l_s[mf], qloc);
      const float rl = 1.f / lsum;
      const int row = b * 2048 + q0 + wave * 32 + mf * 16 + qloc;
#pragma unroll
      for (int jd = 0; jd < 4; ++jd)
        attn[(size_t)row * 1024 + h * 64 + jd * 16 + l15] =
            f32_to_bf16(o[mf][jd][r] * rl);
    }
}

// ---------------------------------------------------------------------------
extern "C" void kernel_launch(void* const* d_in, const int* in_sizes, int n_in,
                              void* d_out, int out_size, void* d_ws, size_t ws_size,
                              hipStream_t stream) {
  const float* x   = (const float*)d_in[0];
  const float* Wq  = (const float*)d_in[1];
  const float* Wk  = (const float*)d_in[2];
  const float* Wv  = (const float*)d_in[3];
  const float* Wo  = (const float*)d_in[4];
  const float* bo  = (const float*)d_in[5];
  const float* W1  = (const float*)d_in[6];
  const float* b1  = (const float*)d_in[7];
  const float* W2  = (const float*)d_in[8];
  const float* b2  = (const float*)d_in[9];
  const float* g1  = (const float*)d_in[10];
  const float* be1 = (const float*)d_in[11];
  const float* g2  = (const float*)d_in[12];
  const float* be2 = (const float*)d_in[13];
  float* out = (float*)d_out;

  char* ws = (char*)d_ws;
  size_t off = 0;
  auto alloc = [&](size_t bytes) -> void* {
    void* p = ws + off;
    off += (bytes + 255) & ~(size_t)255;
    return p;
  };
  unsigned short* WqkvT = (unsigned short*)alloc(3072ull * 1024 * 2);
  unsigned short* WoT   = (unsigned short*)alloc(1024ull * 1024 * 2);
  unsigned short* W1T   = (unsigned short*)alloc(4096ull * 1024 * 2);
  unsigned short* W2T   = (unsigned short*)alloc(1024ull * 4096 * 2);
  unsigned short* nx    = (unsigned short*)alloc(4096ull * 1024 * 2);   // 8 MB
  unsigned short* qkv   = (unsigned short*)alloc(4096ull * 3072 * 2);   // 24 MB
  unsigned short* attn  = (unsigned short*)alloc(4096ull * 1024 * 2);
  float*          x1    = (float*)alloc(4096ull * 1024 * 4);
  unsigned short* nx2   = (unsigned short*)alloc(4096ull * 1024 * 2);
  unsigned short* hbuf  = (unsigned short*)alloc(4096ull * 4096 * 2);
  // vT (8 MB) aliases hbuf: vT written by GEMM1, dead before GEMM3 writes hbuf
  unsigned short* vT    = hbuf;
  // split-K fp32 partials (2 x 16 MB) alias nx+qkv (both dead when used:
  // nx dead after GEMM1; qkv dead after flash; region = exactly 32 MB)
  float*          part  = (float*)nx;

  dim3 blk(256);
  // all four weight transposes in ONE launch (12288 blocks)
  transpose_weights_all<<<dim3(12288), blk, 0, stream>>>(
      Wq, Wk, Wv, Wo, W1, W2, WqkvT, WoT, W1T, W2T);

  layernorm_bf16<<<4096, blk, 0, stream>>>(x, g1, be1, nx);
  // GEMM1: 4096x3072x1024 -> bf16 qkv (Q,K) + V written transposed to vT
  gemm_bf16<<<dim3(24, 32, 1), blk, 0, stream>>>(nx, WqkvT, nullptr, nullptr, qkv, vT, 4096, 3072, 1024, 1024, 0, 4);
  flash_attn_mfma<<<dim3(512, 1, 1), blk, 0, stream>>>(qkv, vT, attn);
  // GEMM2 split-K=2 (fp32 partials) -> fused reduce+LN  (legacy map, L2-fit)
  gemm_bf16<<<dim3(8, 32, 2), blk, 0, stream>>>(attn, WoT, nullptr, nullptr, part, nullptr, 4096, 1024, 1024, 512, 3, 8);
  splitk_reduce_ln<<<4096, blk, 0, stream>>>(part, bo, x, g2, be2, x1, nx2);
  // GEMM3: 4096x4096x1024 relu+bias -> bf16 hbuf  (2D XCD map)
  gemm_bf16<<<dim3(32, 32, 1), blk, 0, stream>>>(nx2, W1T, b1, nullptr, hbuf, nullptr, 4096, 4096, 1024, 1024, 2, 4);
  // GEMM4 split-K=2 (fp32 partials) -> reduce  (legacy map, L2-fit)
  gemm_bf16<<<dim3(8, 32, 2), blk, 0, stream>>>(hbuf, W2T, nullptr, nullptr, part, nullptr, 4096, 1024, 4096, 2048, 3, 8);
  splitk_reduce<<<4096, blk, 0, stream>>>(part, b2, x1, out);
}